// Round 1
// baseline (256.450 us; speedup 1.0000x reference)
//
#include <hip/hip_runtime.h>
#include <math.h>

#define NTOK 16384
#define DIN  128
#define NCH  512
#define CHL  32   // NTOK / NCH

__device__ __forceinline__ float silu_f(float x)    { return x / (1.f + __expf(-x)); }
__device__ __forceinline__ float softplus_f(float x){ return (x > 20.f) ? x : log1pf(__expf(x)); }

// ---------------- K1: LayerNorm(64) + in_proj (64 -> 256), split into x_in / silu(z)
__global__ __launch_bounds__(256) void k1_ln_inproj(
    const float* __restrict__ x, const float* __restrict__ lnw,
    const float* __restrict__ lnb, const float* __restrict__ Win,
    float* __restrict__ xin, float* __restrict__ zbuf)
{
  __shared__ __align__(16) float tl[64*68];    // [c][tok] stride 68
  __shared__ __align__(16) float wt[64*132];   // [c][d(half)] stride 132
  __shared__ float ps[256], pq[256], mu[64], rs[64];

  int t = threadIdx.x;
  int lane = t & 63, grp = t >> 6;
  int b  = blockIdx.x >> 8;           // N/64 = 256 tiles per batch
  int n0 = (blockIdx.x & 255) << 6;
  const float* xb = x + ((size_t)b * 64) * NTOK;

  // load 64ch x 64tok tile, coalesced along n
  for (int i = 0; i < 16; ++i) {
    int c = grp*16 + i;
    tl[c*68 + lane] = xb[(size_t)c*NTOK + n0 + lane];
  }
  __syncthreads();
  // LN: partial sums (4 partials per token)
  float s0 = 0.f, s1 = 0.f;
  for (int i = 0; i < 16; ++i) {
    float v = tl[(grp*16+i)*68 + lane];
    s0 += v; s1 += v*v;
  }
  ps[t] = s0; pq[t] = s1;
  __syncthreads();
  if (t < 64) {
    float m = ps[t] + ps[64+t] + ps[128+t] + ps[192+t];
    float q = pq[t] + pq[64+t] + pq[128+t] + pq[192+t];
    m *= 0.015625f;
    q = q*0.015625f - m*m;
    mu[t] = m; rs[t] = rsqrtf(q + 1e-5f);
  }
  __syncthreads();
  for (int i = 0; i < 16; ++i) {
    int idx = (i<<8) + t;
    int c = idx >> 6, j = idx & 63;
    tl[c*68 + j] = (tl[c*68 + j] - mu[j]) * rs[j] * lnw[c] + lnb[c];
  }

  // in_proj in two d-halves (keeps LDS < 64KB). Each wave-half (32 lanes)
  // covers 128 d x 4 tokens per pass.
  int dl = t & 127, drow = t >> 7;
  int d0 = (lane & 31) << 2;
  int joff = grp*8 + ((lane >> 5) << 2);
  for (int half = 0; half < 2; ++half) {
    __syncthreads();
    for (int i = 0; i < 32; ++i) {
      int c = drow*32 + i;
      wt[c*132 + dl] = Win[((half<<7) + dl)*64 + c];
    }
    __syncthreads();
    for (int p = 0; p < 2; ++p) {
      int jb = joff + (p << 5);
      float acc[4][4] = {{0.f}};
      #pragma unroll 8
      for (int c = 0; c < 64; ++c) {
        float4 tv = *(const float4*)&tl[c*68 + jb];
        float4 wv = *(const float4*)&wt[c*132 + d0];
        acc[0][0] += tv.x*wv.x; acc[0][1] += tv.x*wv.y; acc[0][2] += tv.x*wv.z; acc[0][3] += tv.x*wv.w;
        acc[1][0] += tv.y*wv.x; acc[1][1] += tv.y*wv.y; acc[1][2] += tv.y*wv.z; acc[1][3] += tv.y*wv.w;
        acc[2][0] += tv.z*wv.x; acc[2][1] += tv.z*wv.y; acc[2][2] += tv.z*wv.z; acc[2][3] += tv.z*wv.w;
        acc[3][0] += tv.w*wv.x; acc[3][1] += tv.w*wv.y; acc[3][2] += tv.w*wv.z; acc[3][3] += tv.w*wv.w;
      }
      #pragma unroll
      for (int jj = 0; jj < 4; ++jj) {
        long n = (long)b*NTOK + n0 + jb + jj;
        float4 o = make_float4(acc[jj][0], acc[jj][1], acc[jj][2], acc[jj][3]);
        if (half == 0) {
          *(float4*)&xin[n*128 + d0] = o;
        } else {
          o.x = silu_f(o.x); o.y = silu_f(o.y); o.z = silu_f(o.z); o.w = silu_f(o.w);
          *(float4*)&zbuf[n*128 + d0] = o;
        }
      }
    }
  }
}

// ---------------- K2: depthwise causal conv(k=4) + SiLU
__global__ __launch_bounds__(256) void k2_conv(
    const float* __restrict__ xin, const float* __restrict__ cw,
    const float* __restrict__ cb, float* __restrict__ u)
{
  int t = threadIdx.x;
  int d = t & 127;
  long g = (long)blockIdx.x*2 + (t >> 7);      // global token over B*NTOK
  int n  = (int)(g & (NTOK-1));
  float acc = cb[d];
  #pragma unroll
  for (int k = 0; k < 4; ++k) {
    int m = n - 3 + k;
    if (m >= 0) acc += cw[d*4 + k] * xin[(g - 3 + k)*128 + d];
  }
  u[g*128 + d] = silu_f(acc);
}

// ---------------- K3: x_proj (36 outs) + dt_proj + softplus; writes dt, B, C
__global__ __launch_bounds__(256) void k3_xproj_dt(
    const float* __restrict__ u, const float* __restrict__ Wx,
    const float* __restrict__ Wdt, const float* __restrict__ db,
    float* __restrict__ dt, float* __restrict__ Bm, float* __restrict__ Cm)
{
  __shared__ __align__(16) float wx[36*128];
  __shared__ float wdtT[4*128];
  int t = threadIdx.x;
  for (int i = t; i < 1152; i += 256)
    *(float4*)&wx[i*4] = *(const float4*)&Wx[i*4];
  for (int i = t; i < 512; i += 256)
    wdtT[(i&3)*128 + (i>>2)] = Wdt[i];
  __syncthreads();

  int lane = t & 63, wv = t >> 6;
  long tokbase = (long)blockIdx.x*32 + wv*8;
  for (int j = 0; j < 8; ++j) {
    long tok = tokbase + j;
    float u0 = u[tok*128 + lane];
    float u1 = u[tok*128 + 64 + lane];
    float xr[4];
    float bval = 0.f, cval = 0.f;
    #pragma unroll
    for (int e = 0; e < 4; ++e) {
      float p = u0*wx[e*128 + lane] + u1*wx[e*128 + 64 + lane];
      p += __shfl_xor(p, 1);  p += __shfl_xor(p, 2);  p += __shfl_xor(p, 4);
      p += __shfl_xor(p, 8);  p += __shfl_xor(p, 16); p += __shfl_xor(p, 32);
      xr[e] = p;
    }
    #pragma unroll
    for (int e = 4; e < 20; ++e) {
      float p = u0*wx[e*128 + lane] + u1*wx[e*128 + 64 + lane];
      p += __shfl_xor(p, 1);  p += __shfl_xor(p, 2);  p += __shfl_xor(p, 4);
      p += __shfl_xor(p, 8);  p += __shfl_xor(p, 16); p += __shfl_xor(p, 32);
      if (lane == e-4) bval = p;
    }
    #pragma unroll
    for (int e = 20; e < 36; ++e) {
      float p = u0*wx[e*128 + lane] + u1*wx[e*128 + 64 + lane];
      p += __shfl_xor(p, 1);  p += __shfl_xor(p, 2);  p += __shfl_xor(p, 4);
      p += __shfl_xor(p, 8);  p += __shfl_xor(p, 16); p += __shfl_xor(p, 32);
      if (lane == e-20) cval = p;
    }
    if (lane < 16) { Bm[tok*16 + lane] = bval; Cm[tok*16 + lane] = cval; }
    #pragma unroll
    for (int dh = 0; dh < 2; ++dh) {
      int d = dh*64 + lane;
      float a = db[d] + xr[0]*wdtT[d] + xr[1]*wdtT[128+d]
                      + xr[2]*wdtT[256+d] + xr[3]*wdtT[384+d];
      dt[tok*128 + d] = softplus_f(a);
    }
  }
}

// ---------------- K4A: per-chunk local scan -> carries (prodA, hLocal)
__global__ __launch_bounds__(128) void k4a_local(
    const float* __restrict__ dt, const float* __restrict__ u,
    const float* __restrict__ Bm, const float* __restrict__ Alog,
    float* __restrict__ carP, float* __restrict__ carH)
{
  int d = threadIdx.x;
  int b = blockIdx.x / NCH, ch = blockIdx.x % NCH;
  long nb = (long)b*NTOK + (long)ch*CHL;
  float A[16], h[16], P[16];
  #pragma unroll
  for (int k = 0; k < 4; ++k) {
    float4 a = *(const float4*)&Alog[d*16 + k*4];
    A[k*4+0] = -__expf(a.x); A[k*4+1] = -__expf(a.y);
    A[k*4+2] = -__expf(a.z); A[k*4+3] = -__expf(a.w);
  }
  #pragma unroll
  for (int s = 0; s < 16; ++s) { h[s] = 0.f; P[s] = 1.f; }
  for (int i = 0; i < CHL; ++i) {
    long n = nb + i;
    float dtv = dt[n*128 + d];
    float uv  = u [n*128 + d];
    float du  = dtv * uv;
    float Bv[16];
    #pragma unroll
    for (int k = 0; k < 4; ++k) {
      float4 v = *(const float4*)&Bm[n*16 + k*4];
      Bv[k*4]=v.x; Bv[k*4+1]=v.y; Bv[k*4+2]=v.z; Bv[k*4+3]=v.w;
    }
    #pragma unroll
    for (int s = 0; s < 16; ++s) {
      float dA = __expf(dtv * A[s]);
      h[s] = dA*h[s] + du*Bv[s];
      P[s] *= dA;
    }
  }
  long cbs = ((long)(b*NCH + ch)*128 + d) * 16;
  #pragma unroll
  for (int k = 0; k < 4; ++k) {
    *(float4*)&carP[cbs + k*4] = make_float4(P[k*4],P[k*4+1],P[k*4+2],P[k*4+3]);
    *(float4*)&carH[cbs + k*4] = make_float4(h[k*4],h[k*4+1],h[k*4+2],h[k*4+3]);
  }
}

// ---------------- K4B: sequential scan over chunk carries -> exclusive prefix h_in
__global__ __launch_bounds__(256) void k4b_carry(
    const float* __restrict__ cP, const float* __restrict__ cH,
    float* __restrict__ hin)
{
  int idx = blockIdx.x*256 + threadIdx.x;   // b*2048 + d*16 + s
  int b = idx >> 11;
  int rem = idx & 2047;
  float h = 0.f;
  for (int ch = 0; ch < NCH; ++ch) {
    long a = ((long)b*NCH + ch)*2048 + rem;
    hin[a] = h;
    h = cP[a]*h + cH[a];
  }
}

// ---------------- K4C: re-run chunks with carry-in, fuse C-contraction, +uD, *silu(z)
__global__ __launch_bounds__(128) void k4c_apply(
    const float* __restrict__ dt, const float* __restrict__ u,
    const float* __restrict__ Bm, const float* __restrict__ Cm,
    const float* __restrict__ Alog, const float* __restrict__ Dp,
    const float* __restrict__ zs, const float* __restrict__ hin,
    float* __restrict__ yz)
{
  int d = threadIdx.x;
  int b = blockIdx.x / NCH, ch = blockIdx.x % NCH;
  long nb = (long)b*NTOK + (long)ch*CHL;
  float A[16], h[16];
  #pragma unroll
  for (int k = 0; k < 4; ++k) {
    float4 a = *(const float4*)&Alog[d*16 + k*4];
    A[k*4+0] = -__expf(a.x); A[k*4+1] = -__expf(a.y);
    A[k*4+2] = -__expf(a.z); A[k*4+3] = -__expf(a.w);
  }
  long cbs = ((long)(b*NCH + ch)*128 + d) * 16;
  #pragma unroll
  for (int k = 0; k < 4; ++k) {
    float4 v = *(const float4*)&hin[cbs + k*4];
    h[k*4]=v.x; h[k*4+1]=v.y; h[k*4+2]=v.z; h[k*4+3]=v.w;
  }
  float Dv = Dp[d];
  for (int i = 0; i < CHL; ++i) {
    long n = nb + i;
    float dtv = dt[n*128 + d];
    float uv  = u [n*128 + d];
    float du  = dtv * uv;
    float Bv[16], Cv[16];
    #pragma unroll
    for (int k = 0; k < 4; ++k) {
      float4 v = *(const float4*)&Bm[n*16 + k*4];
      Bv[k*4]=v.x; Bv[k*4+1]=v.y; Bv[k*4+2]=v.z; Bv[k*4+3]=v.w;
      float4 w = *(const float4*)&Cm[n*16 + k*4];
      Cv[k*4]=w.x; Cv[k*4+1]=w.y; Cv[k*4+2]=w.z; Cv[k*4+3]=w.w;
    }
    float y = 0.f;
    #pragma unroll
    for (int s = 0; s < 16; ++s) {
      float dA = __expf(dtv * A[s]);
      h[s] = dA*h[s] + du*Bv[s];
      y += h[s]*Cv[s];
    }
    y = (y + uv*Dv) * zs[n*128 + d];
    yz[n*128 + d] = y;
  }
}

// ---------------- K6: out_proj (128 -> 64) + bias, write (B,C,N)
__global__ __launch_bounds__(256) void k6_outproj(
    const float* __restrict__ yz, const float* __restrict__ Wout,
    const float* __restrict__ ob, float* __restrict__ out)
{
  __shared__ __align__(16) float wo[64*132];   // [c][d] stride 132
  __shared__ __align__(16) float yl[32*132];   // [tok][d] stride 132
  int t = threadIdx.x;
  long tok0 = (long)blockIdx.x * 32;
  for (int i = 0; i < 8; ++i) {
    int g = i*256 + t; int c = g >> 5, q = g & 31;
    *(float4*)&wo[c*132 + q*4] = *(const float4*)&Wout[c*128 + q*4];
  }
  for (int i = 0; i < 4; ++i) {
    int g = i*256 + t; int tok = g >> 5, q = g & 31;
    *(float4*)&yl[tok*132 + q*4] = *(const float4*)&yz[(tok0 + tok)*128 + q*4];
  }
  __syncthreads();
  int tp = t & 15;      // c base (interleaved: c = tp + 16*cc)
  int tg = t >> 4;      // token base (tok = tg + 16*tt)
  float acc[4][2] = {{0.f}};
  for (int d4 = 0; d4 < 32; ++d4) {
    float4 y0 = *(const float4*)&yl[tg*132 + d4*4];
    float4 y1 = *(const float4*)&yl[(tg+16)*132 + d4*4];
    #pragma unroll
    for (int cc = 0; cc < 4; ++cc) {
      float4 wv = *(const float4*)&wo[(tp + 16*cc)*132 + d4*4];
      acc[cc][0] += wv.x*y0.x + wv.y*y0.y + wv.z*y0.z + wv.w*y0.w;
      acc[cc][1] += wv.x*y1.x + wv.y*y1.y + wv.z*y1.z + wv.w*y1.w;
    }
  }
  int b  = (int)(tok0 / NTOK);
  long n0 = tok0 % NTOK;
  #pragma unroll
  for (int cc = 0; cc < 4; ++cc) {
    int c = tp + 16*cc;
    float bias = ob[c];
    out[((long)b*64 + c)*NTOK + n0 + tg     ] = acc[cc][0] + bias;
    out[((long)b*64 + c)*NTOK + n0 + tg + 16] = acc[cc][1] + bias;
  }
}

extern "C" void kernel_launch(void* const* d_in, const int* in_sizes, int n_in,
                              void* d_out, int out_size, void* d_ws, size_t ws_size,
                              hipStream_t stream)
{
  (void)in_sizes; (void)n_in; (void)out_size; (void)ws_size;
  const float* x    = (const float*)d_in[0];
  const float* lnw  = (const float*)d_in[1];
  const float* lnb  = (const float*)d_in[2];
  const float* Win  = (const float*)d_in[3];
  const float* cw   = (const float*)d_in[4];
  const float* cb   = (const float*)d_in[5];
  const float* Wx   = (const float*)d_in[6];
  const float* Wdt  = (const float*)d_in[7];
  const float* db   = (const float*)d_in[8];
  const float* Alog = (const float*)d_in[9];
  const float* Dp   = (const float*)d_in[10];
  const float* Wout = (const float*)d_in[11];
  const float* ob   = (const float*)d_in[12];
  float* out = (float*)d_out;

  float* w   = (float*)d_ws;
  float* xin = w;                 // 4,194,304 floats; reused as yz after K4C
  float* z   = w + 4194304;       // silu(z)
  float* u   = w + 8388608;
  float* dt  = w + 12582912;
  float* Bm  = w + 16777216;      // 524,288
  float* Cm  = w + 17301504;      // 524,288
  float* cP  = w + 17825792;      // 2,097,152
  float* cH  = w + 19922944;      // 2,097,152
  float* hin = w + 22020096;      // 2,097,152  (total 96.5 MB)

  k1_ln_inproj<<<512,  256, 0, stream>>>(x, lnw, lnb, Win, xin, z);
  k2_conv     <<<16384,256, 0, stream>>>(xin, cw, cb, u);
  k3_xproj_dt <<<1024, 256, 0, stream>>>(u, Wx, Wdt, db, dt, Bm, Cm);
  k4a_local   <<<1024, 128, 0, stream>>>(dt, u, Bm, Alog, cP, cH);
  k4b_carry   <<<16,   256, 0, stream>>>(cP, cH, hin);
  k4c_apply   <<<1024, 128, 0, stream>>>(dt, u, Bm, Cm, Alog, Dp, z, hin, xin);
  k6_outproj  <<<1024, 256, 0, stream>>>(xin, Wout, ob, out);
}

// Round 2
// 164.441 us; speedup vs baseline: 1.5595x; 1.5595x over previous
//
#include <hip/hip_runtime.h>
#include <math.h>

#define NTOK 16384
#define DIN  128
#define NCH  512
#define CHL  32   // NTOK / NCH
#define NG   16   // carry-scan groups (32 chunks each)

__device__ __forceinline__ float silu_f(float x)    { return x / (1.f + __expf(-x)); }
__device__ __forceinline__ float softplus_f(float x){ return (x > 20.f) ? x : log1pf(__expf(x)); }

// ---------------- K1: LayerNorm(64) + in_proj (64 -> 256), split into x_in / silu(z)
__global__ __launch_bounds__(256) void k1_ln_inproj(
    const float* __restrict__ x, const float* __restrict__ lnw,
    const float* __restrict__ lnb, const float* __restrict__ Win,
    float* __restrict__ xin, float* __restrict__ zbuf)
{
  __shared__ __align__(16) float tl[64*68];    // [c][tok] stride 68
  __shared__ __align__(16) float wt[64*132];   // [c][d(half)] stride 132
  __shared__ float ps[256], pq[256], mu[64], rs[64];

  int t = threadIdx.x;
  int lane = t & 63, grp = t >> 6;
  int b  = blockIdx.x >> 8;           // N/64 = 256 tiles per batch
  int n0 = (blockIdx.x & 255) << 6;
  const float* xb = x + ((size_t)b * 64) * NTOK;

  for (int i = 0; i < 16; ++i) {
    int c = grp*16 + i;
    tl[c*68 + lane] = xb[(size_t)c*NTOK + n0 + lane];
  }
  __syncthreads();
  float s0 = 0.f, s1 = 0.f;
  for (int i = 0; i < 16; ++i) {
    float v = tl[(grp*16+i)*68 + lane];
    s0 += v; s1 += v*v;
  }
  ps[t] = s0; pq[t] = s1;
  __syncthreads();
  if (t < 64) {
    float m = ps[t] + ps[64+t] + ps[128+t] + ps[192+t];
    float q = pq[t] + pq[64+t] + pq[128+t] + pq[192+t];
    m *= 0.015625f;
    q = q*0.015625f - m*m;
    mu[t] = m; rs[t] = rsqrtf(q + 1e-5f);
  }
  __syncthreads();
  for (int i = 0; i < 16; ++i) {
    int idx = (i<<8) + t;
    int c = idx >> 6, j = idx & 63;
    tl[c*68 + j] = (tl[c*68 + j] - mu[j]) * rs[j] * lnw[c] + lnb[c];
  }

  int dl = t & 127, drow = t >> 7;
  int d0 = (lane & 31) << 2;
  int joff = grp*8 + ((lane >> 5) << 2);
  for (int half = 0; half < 2; ++half) {
    __syncthreads();
    for (int i = 0; i < 32; ++i) {
      int c = drow*32 + i;
      wt[c*132 + dl] = Win[((half<<7) + dl)*64 + c];
    }
    __syncthreads();
    for (int p = 0; p < 2; ++p) {
      int jb = joff + (p << 5);
      float acc[4][4] = {{0.f}};
      #pragma unroll 8
      for (int c = 0; c < 64; ++c) {
        float4 tv = *(const float4*)&tl[c*68 + jb];
        float4 wv = *(const float4*)&wt[c*132 + d0];
        acc[0][0] += tv.x*wv.x; acc[0][1] += tv.x*wv.y; acc[0][2] += tv.x*wv.z; acc[0][3] += tv.x*wv.w;
        acc[1][0] += tv.y*wv.x; acc[1][1] += tv.y*wv.y; acc[1][2] += tv.y*wv.z; acc[1][3] += tv.y*wv.w;
        acc[2][0] += tv.z*wv.x; acc[2][1] += tv.z*wv.y; acc[2][2] += tv.z*wv.z; acc[2][3] += tv.z*wv.w;
        acc[3][0] += tv.w*wv.x; acc[3][1] += tv.w*wv.y; acc[3][2] += tv.w*wv.z; acc[3][3] += tv.w*wv.w;
      }
      #pragma unroll
      for (int jj = 0; jj < 4; ++jj) {
        long n = (long)b*NTOK + n0 + jb + jj;
        float4 o = make_float4(acc[jj][0], acc[jj][1], acc[jj][2], acc[jj][3]);
        if (half == 0) {
          *(float4*)&xin[n*128 + d0] = o;
        } else {
          o.x = silu_f(o.x); o.y = silu_f(o.y); o.z = silu_f(o.z); o.w = silu_f(o.w);
          *(float4*)&zbuf[n*128 + d0] = o;
        }
      }
    }
  }
}

// ---------------- K2: depthwise causal conv(k=4) + SiLU
__global__ __launch_bounds__(256) void k2_conv(
    const float* __restrict__ xin, const float* __restrict__ cw,
    const float* __restrict__ cb, float* __restrict__ u)
{
  int t = threadIdx.x;
  int d = t & 127;
  long g = (long)blockIdx.x*2 + (t >> 7);      // global token over B*NTOK
  int n  = (int)(g & (NTOK-1));
  float acc = cb[d];
  #pragma unroll
  for (int k = 0; k < 4; ++k) {
    int m = n - 3 + k;
    if (m >= 0) acc += cw[d*4 + k] * xin[(g - 3 + k)*128 + d];
  }
  u[g*128 + d] = silu_f(acc);
}

// ---------------- K3: x_proj (36 outs) + dt_proj + softplus (reduction-free)
__global__ __launch_bounds__(256) void k3_xproj_dt(
    const float* __restrict__ u, const float* __restrict__ Wx,
    const float* __restrict__ Wdt, const float* __restrict__ db,
    float* __restrict__ dt, float* __restrict__ Bm, float* __restrict__ Cm)
{
  __shared__ __align__(16) float wx[36*128];   // 18.4 KB
  __shared__ float wdtT[4*128];                // 2 KB   (transposed: [r][d])
  __shared__ __align__(16) float xdbl[64*40];  // 10.2 KB (stride 40)
  int t = threadIdx.x;
  for (int i = t; i < 1152; i += 256)
    *(float4*)&wx[i*4] = *(const float4*)&Wx[i*4];
  for (int i = t; i < 512; i += 256)
    wdtT[(i&3)*128 + (i>>2)] = Wdt[i];
  __syncthreads();

  long tok0 = (long)blockIdx.x * 64;
  int tok = t & 63, grp = t >> 6;      // grp owns e in [grp*9, grp*9+9)
  const float* urow = u + (tok0 + tok)*128;

  float acc[9];
  #pragma unroll
  for (int e = 0; e < 9; ++e) acc[e] = 0.f;
  #pragma unroll 8
  for (int d4 = 0; d4 < 32; ++d4) {
    float4 uv = *(const float4*)&urow[d4*4];
    #pragma unroll
    for (int e = 0; e < 9; ++e) {
      float4 wv = *(const float4*)&wx[(grp*9+e)*128 + d4*4];
      acc[e] += uv.x*wv.x + uv.y*wv.y + uv.z*wv.z + uv.w*wv.w;
    }
  }
  #pragma unroll
  for (int e = 0; e < 9; ++e) xdbl[tok*40 + grp*9 + e] = acc[e];
  __syncthreads();

  // B/C: 64 tok x 16 each, via float4
  {
    int tk = t >> 2, q = t & 3;
    float4 bv = *(const float4*)&xdbl[tk*40 + 4  + q*4];
    float4 cv = *(const float4*)&xdbl[tk*40 + 20 + q*4];
    *(float4*)&Bm[(tok0+tk)*16 + q*4] = bv;
    *(float4*)&Cm[(tok0+tk)*16 + q*4] = cv;
  }
  // dt: d = t&127, half of tokens per thread-row
  int d = t & 127, th = t >> 7;
  float w0 = wdtT[d], w1 = wdtT[128+d], w2 = wdtT[256+d], w3 = wdtT[384+d];
  float bias = db[d];
  for (int j = 0; j < 32; ++j) {
    int tk = th*32 + j;
    float a = bias + xdbl[tk*40]*w0 + xdbl[tk*40+1]*w1
                   + xdbl[tk*40+2]*w2 + xdbl[tk*40+3]*w3;
    dt[(tok0+tk)*128 + d] = softplus_f(a);
  }
}

// ---------------- K4A: per-chunk local scan -> carries (prodA, hLocal)
__global__ __launch_bounds__(128) void k4a_local(
    const float* __restrict__ dt, const float* __restrict__ u,
    const float* __restrict__ Bm, const float* __restrict__ Alog,
    float* __restrict__ carP, float* __restrict__ carH)
{
  int d = threadIdx.x;
  int b = blockIdx.x / NCH, ch = blockIdx.x % NCH;
  long nb = (long)b*NTOK + (long)ch*CHL;
  float A[16], h[16], P[16];
  #pragma unroll
  for (int k = 0; k < 4; ++k) {
    float4 a = *(const float4*)&Alog[d*16 + k*4];
    A[k*4+0] = -__expf(a.x); A[k*4+1] = -__expf(a.y);
    A[k*4+2] = -__expf(a.z); A[k*4+3] = -__expf(a.w);
  }
  #pragma unroll
  for (int s = 0; s < 16; ++s) { h[s] = 0.f; P[s] = 1.f; }
  for (int i = 0; i < CHL; ++i) {
    long n = nb + i;
    float dtv = dt[n*128 + d];
    float uv  = u [n*128 + d];
    float du  = dtv * uv;
    float Bv[16];
    #pragma unroll
    for (int k = 0; k < 4; ++k) {
      float4 v = *(const float4*)&Bm[n*16 + k*4];
      Bv[k*4]=v.x; Bv[k*4+1]=v.y; Bv[k*4+2]=v.z; Bv[k*4+3]=v.w;
    }
    #pragma unroll
    for (int s = 0; s < 16; ++s) {
      float dA = __expf(dtv * A[s]);
      h[s] = dA*h[s] + du*Bv[s];
      P[s] *= dA;
    }
  }
  long cbs = ((long)(b*NCH + ch)*128 + d) * 16;
  #pragma unroll
  for (int k = 0; k < 4; ++k) {
    *(float4*)&carP[cbs + k*4] = make_float4(P[k*4],P[k*4+1],P[k*4+2],P[k*4+3]);
    *(float4*)&carH[cbs + k*4] = make_float4(h[k*4],h[k*4+1],h[k*4+2],h[k*4+3]);
  }
}

// ---------------- K4B1: scan 32-chunk groups; exclusive prefixes in place + group carries
__global__ __launch_bounds__(256) void k4b1_group(
    float* __restrict__ cP, float* __restrict__ cH,
    float* __restrict__ Pg, float* __restrict__ Hg)
{
  int idx = blockIdx.x*256 + threadIdx.x;   // [0, B*NG*2048)
  int rem = idx & 2047;
  int g   = (idx >> 11) & (NG-1);
  int b   = idx >> 15;
  float P = 1.f, H = 0.f;
  long base = ((long)b*NCH + g*32)*2048 + rem;
  for (int j = 0; j < 32; ++j) {
    long a = base + (long)j*2048;
    float p = cP[a], h = cH[a];
    cP[a] = P; cH[a] = H;          // exclusive within-group prefixes
    H = p*H + h;
    P = p*P;
  }
  long ga = ((long)b*NG + g)*2048 + rem;
  Pg[ga] = P; Hg[ga] = H;
}

// ---------------- K4B2: tiny scan over NG group carries -> exclusive Hg in place
__global__ __launch_bounds__(256) void k4b2_carry(
    const float* __restrict__ Pg, float* __restrict__ Hg)
{
  int idx = blockIdx.x*256 + threadIdx.x;  // [0, B*2048)
  int b = idx >> 11, rem = idx & 2047;
  float H = 0.f;
  for (int g = 0; g < NG; ++g) {
    long a = ((long)b*NG + g)*2048 + rem;
    float p = Pg[a], h = Hg[a];
    Hg[a] = H;
    H = p*H + h;
  }
}

// ---------------- K4C: re-run chunks with composed carry-in; fuse C-contraction, +uD, *silu(z)
__global__ __launch_bounds__(128) void k4c_apply(
    const float* __restrict__ dt, const float* __restrict__ u,
    const float* __restrict__ Bm, const float* __restrict__ Cm,
    const float* __restrict__ Alog, const float* __restrict__ Dp,
    const float* __restrict__ zs, const float* __restrict__ pPre,
    const float* __restrict__ hPre, const float* __restrict__ Hg,
    float* __restrict__ yz)
{
  int d = threadIdx.x;
  int b = blockIdx.x / NCH, ch = blockIdx.x % NCH;
  long nb = (long)b*NTOK + (long)ch*CHL;
  float A[16], h[16];
  #pragma unroll
  for (int k = 0; k < 4; ++k) {
    float4 a = *(const float4*)&Alog[d*16 + k*4];
    A[k*4+0] = -__expf(a.x); A[k*4+1] = -__expf(a.y);
    A[k*4+2] = -__expf(a.z); A[k*4+3] = -__expf(a.w);
  }
  long cbs = ((long)(b*NCH + ch)*128 + d) * 16;
  long gbs = ((long)b*NG + (ch >> 5))*2048 + d*16;
  #pragma unroll
  for (int k = 0; k < 4; ++k) {
    float4 hp = *(const float4*)&hPre[cbs + k*4];
    float4 pp = *(const float4*)&pPre[cbs + k*4];
    float4 gi = *(const float4*)&Hg[gbs + k*4];
    h[k*4+0] = hp.x + pp.x*gi.x; h[k*4+1] = hp.y + pp.y*gi.y;
    h[k*4+2] = hp.z + pp.z*gi.z; h[k*4+3] = hp.w + pp.w*gi.w;
  }
  float Dv = Dp[d];
  for (int i = 0; i < CHL; ++i) {
    long n = nb + i;
    float dtv = dt[n*128 + d];
    float uv  = u [n*128 + d];
    float du  = dtv * uv;
    float Bv[16], Cv[16];
    #pragma unroll
    for (int k = 0; k < 4; ++k) {
      float4 v = *(const float4*)&Bm[n*16 + k*4];
      Bv[k*4]=v.x; Bv[k*4+1]=v.y; Bv[k*4+2]=v.z; Bv[k*4+3]=v.w;
      float4 w = *(const float4*)&Cm[n*16 + k*4];
      Cv[k*4]=w.x; Cv[k*4+1]=w.y; Cv[k*4+2]=w.z; Cv[k*4+3]=w.w;
    }
    float y = 0.f;
    #pragma unroll
    for (int s = 0; s < 16; ++s) {
      float dA = __expf(dtv * A[s]);
      h[s] = dA*h[s] + du*Bv[s];
      y += h[s]*Cv[s];
    }
    y = (y + uv*Dv) * zs[n*128 + d];
    yz[n*128 + d] = y;
  }
}

// ---------------- K6: out_proj (128 -> 64) + bias, write (B,C,N)
__global__ __launch_bounds__(256) void k6_outproj(
    const float* __restrict__ yz, const float* __restrict__ Wout,
    const float* __restrict__ ob, float* __restrict__ out)
{
  __shared__ __align__(16) float wo[64*132];   // [c][d] stride 132
  __shared__ __align__(16) float yl[32*132];   // [tok][d] stride 132
  int t = threadIdx.x;
  long tok0 = (long)blockIdx.x * 32;
  for (int i = 0; i < 8; ++i) {
    int g = i*256 + t; int c = g >> 5, q = g & 31;
    *(float4*)&wo[c*132 + q*4] = *(const float4*)&Wout[c*128 + q*4];
  }
  for (int i = 0; i < 4; ++i) {
    int g = i*256 + t; int tok = g >> 5, q = g & 31;
    *(float4*)&yl[tok*132 + q*4] = *(const float4*)&yz[(tok0 + tok)*128 + q*4];
  }
  __syncthreads();
  int tp = t & 15;
  int tg = t >> 4;
  float acc[4][2] = {{0.f}};
  for (int d4 = 0; d4 < 32; ++d4) {
    float4 y0 = *(const float4*)&yl[tg*132 + d4*4];
    float4 y1 = *(const float4*)&yl[(tg+16)*132 + d4*4];
    #pragma unroll
    for (int cc = 0; cc < 4; ++cc) {
      float4 wv = *(const float4*)&wo[(tp + 16*cc)*132 + d4*4];
      acc[cc][0] += wv.x*y0.x + wv.y*y0.y + wv.z*y0.z + wv.w*y0.w;
      acc[cc][1] += wv.x*y1.x + wv.y*y1.y + wv.z*y1.z + wv.w*y1.w;
    }
  }
  int b  = (int)(tok0 / NTOK);
  long n0 = tok0 % NTOK;
  #pragma unroll
  for (int cc = 0; cc < 4; ++cc) {
    int c = tp + 16*cc;
    float bias = ob[c];
    out[((long)b*64 + c)*NTOK + n0 + tg     ] = acc[cc][0] + bias;
    out[((long)b*64 + c)*NTOK + n0 + tg + 16] = acc[cc][1] + bias;
  }
}

extern "C" void kernel_launch(void* const* d_in, const int* in_sizes, int n_in,
                              void* d_out, int out_size, void* d_ws, size_t ws_size,
                              hipStream_t stream)
{
  (void)in_sizes; (void)n_in; (void)out_size; (void)ws_size;
  const float* x    = (const float*)d_in[0];
  const float* lnw  = (const float*)d_in[1];
  const float* lnb  = (const float*)d_in[2];
  const float* Win  = (const float*)d_in[3];
  const float* cw   = (const float*)d_in[4];
  const float* cb   = (const float*)d_in[5];
  const float* Wx   = (const float*)d_in[6];
  const float* Wdt  = (const float*)d_in[7];
  const float* db   = (const float*)d_in[8];
  const float* Alog = (const float*)d_in[9];
  const float* Dp   = (const float*)d_in[10];
  const float* Wout = (const float*)d_in[11];
  const float* ob   = (const float*)d_in[12];
  float* out = (float*)d_out;

  float* w   = (float*)d_ws;
  float* xin = w;                 // 4,194,304 floats; reused as yz after K4C
  float* z   = w + 4194304;
  float* u   = w + 8388608;
  float* dt  = w + 12582912;
  float* Bm  = w + 16777216;
  float* Cm  = w + 17301504;
  float* cP  = w + 17825792;      // 2,097,152 (becomes exclusive P-prefix)
  float* cH  = w + 19922944;      // 2,097,152 (becomes exclusive h-prefix)
  float* Pg  = w + 22020096;      // 65,536
  float* Hg  = w + 22085632;      // 65,536

  k1_ln_inproj<<<512,  256, 0, stream>>>(x, lnw, lnb, Win, xin, z);
  k2_conv     <<<16384,256, 0, stream>>>(xin, cw, cb, u);
  k3_xproj_dt <<<512,  256, 0, stream>>>(u, Wx, Wdt, db, dt, Bm, Cm);
  k4a_local   <<<1024, 128, 0, stream>>>(dt, u, Bm, Alog, cP, cH);
  k4b1_group  <<<256,  256, 0, stream>>>(cP, cH, Pg, Hg);
  k4b2_carry  <<<16,   256, 0, stream>>>(Pg, Hg);
  k4c_apply   <<<1024, 128, 0, stream>>>(dt, u, Bm, Cm, Alog, Dp, z, cP, cH, Hg, xin);
  k6_outproj  <<<1024, 256, 0, stream>>>(xin, Wout, ob, out);
}